// Round 6
// baseline (7220.351 us; speedup 1.0000x reference)
//
#include <hip/hip_runtime.h>
#include <math.h>

#define BB 64
#define TT 32
#define II 512
#define HH 1024
#define OO 512
#define NN 1024
#define MM 64
#define EPSF 1e-8f

#define NROWA 3852   // 3072 Whh + 512 Who + 268 gate rows (all dot h, k=1024)
#define NGATE 268

// global layouts:
//  hT4  [k4 0..255][b 0..63][4]
//  xiT4 [k4 0..127][b 0..63][4]
//  YT   [row 0..3071][b]   (Whh·h + bhh)
//  GY   [g 0..267][b]      (activated gate values; s-rows raw)
//  memT [b][m][n]
// LDS per block: WaL[16][1024] (its 16 h-GEMV rows), WbL[12][512] (its 12 gi rows), work[4160]

struct P {
  const float *Wk_r,*bk_r,*Wb_r,*bb_r,*Wg_r,*bg_r,*Ws_r,*bs_r,*Wga_r,*bga_r;
  const float *Wk_w,*bk_w,*Wb_w,*bb_w,*Wg_w,*bg_w,*Ws_w,*bs_w,*Wga_w,*bga_w;
  const float *We,*be,*Wa,*ba,*W_r2i,*b_r2i,*Wih,*bih,*Whh,*bhh,*Who,*bho;
  const float *x, *mem0;
  float *outs, *wr, *ww, *memOut, *h;       // outputs
  float *hT4, *YT, *GY, *xiT4, *W_r2iT, *memT;
  int *flags, *go;
};

__device__ __forceinline__ float sigmf(float x){ return 1.f/(1.f+expf(-x)); }
__device__ __forceinline__ float splusf(float x){ return fmaxf(x,0.f) + log1pf(expf(-fabsf(x))); }
__device__ __forceinline__ float4 ld4(const float* p){ return *reinterpret_cast<const float4*>(p); }
__device__ __forceinline__ void st4(float* p, float4 v){ *reinterpret_cast<float4*>(p) = v; }
__device__ __forceinline__ float wredsum(float v){
  #pragma unroll
  for (int o = 32; o; o >>= 1) v += __shfl_xor(v, o);
  return v;
}
__device__ __forceinline__ float wredmax(float v){
  #pragma unroll
  for (int o = 32; o; o >>= 1) v = fmaxf(v, __shfl_xor(v, o));
  return v;
}
// NOTE: a macro with a parameter named `w` breaks on member access `.w` — real function.
__device__ __forceinline__ float dot4f(float a, float4 wv, float4 vv){
  return fmaf(wv.x, vv.x, fmaf(wv.y, vv.y, fmaf(wv.z, vv.z, fmaf(wv.w, vv.w, a))));
}

// ---------------- lean epoch grid barrier ----------------
// producers: release-store own flag; block 0 watches all flags (1 per thread,
// parallel), then release-stores `go`; everyone polls `go` relaxed + s_sleep.
// No contended RMW, no system-scope flush (agent scope spans all XCDs).
__device__ void gbar(int* flags, int* go, int e) {
  __syncthreads();
  if (blockIdx.x == 0) {
    if (threadIdx.x > 0 && threadIdx.x < 256) {
      while (__hip_atomic_load(&flags[threadIdx.x], __ATOMIC_RELAXED, __HIP_MEMORY_SCOPE_AGENT) < e)
        __builtin_amdgcn_s_sleep(2);
    }
    __syncthreads();
    __builtin_amdgcn_fence(__ATOMIC_ACQ_REL, "agent");
    if (threadIdx.x == 0)
      __hip_atomic_store(go, e, __ATOMIC_RELEASE, __HIP_MEMORY_SCOPE_AGENT);
    __syncthreads();
  } else {
    if (threadIdx.x == 0) {
      __hip_atomic_store(&flags[blockIdx.x], e, __ATOMIC_RELEASE, __HIP_MEMORY_SCOPE_AGENT);
      while (__hip_atomic_load(go, __ATOMIC_RELAXED, __HIP_MEMORY_SCOPE_AGENT) < e)
        __builtin_amdgcn_s_sleep(2);
    }
    __syncthreads();
    __builtin_amdgcn_fence(__ATOMIC_ACQUIRE, "agent");
  }
}

// gate row descriptor (g in [0,268))
__device__ const float* gate_src(const P& p, int g, float& bias, int& act) {
  if (g < 140) {
    const int head = (g >= 70);
    const int q = g - head*70;
    if (q < 64)  { bias = (head?p.bk_w:p.bk_r)[q]; act=0; return (head?p.Wk_w:p.Wk_r)+(size_t)q*HH; }
    if (q == 64) { bias = (head?p.bb_w:p.bb_r)[0]; act=1; return head?p.Wb_w:p.Wb_r; }
    if (q == 65) { bias = (head?p.bg_w:p.bg_r)[0]; act=2; return head?p.Wg_w:p.Wg_r; }
    if (q < 69)  { bias = (head?p.bs_w:p.bs_r)[q-66]; act=5; return (head?p.Ws_w:p.Ws_r)+(size_t)(q-66)*HH; }
    bias = (head?p.bga_w:p.bga_r)[0]; act=4; return head?p.Wga_w:p.Wga_r;
  }
  if (g < 204) { const int m=g-140; bias=p.be[m]; act=2; return p.We+(size_t)m*HH; }
  const int m = g-204; bias=p.ba[m]; act=0; return p.Wa+(size_t)m*HH;
}

__device__ void emitA(const P& p, int r, float acc, int t, int lane) {
  if (r < 3072) {
    p.YT[(size_t)r*64 + lane] = acc + p.bhh[r];
  } else if (r < 3584) {
    const int o = r - 3072;
    if (t >= 1) p.outs[((size_t)lane*TT + (t-1))*OO + o] = sigmf(acc + p.bho[o]);
  } else {
    const int g = r - 3584;
    float bias; int act;
    gate_src(p, g, bias, act);
    float v = acc + bias;
    if (act==0) v = tanhf(v);
    else if (act==1) v = splusf(v);
    else if (act==2) v = sigmf(v);
    else if (act==4) v = 1.f + splusf(v);
    p.GY[(size_t)g*64 + lane] = v;
  }
}

// -------- phase A: h-GEMV from LDS weights, lanes=b, 2 rows/wave (waves 0..7) --------
__device__ void phaseA(const P& p, const float* WaL, int t, int blk, int wv, int lane) {
  if (wv >= 8) return;
  const int r0 = blk*16 + wv*2;
  const int r1 = r0 + 1;
  if (r0 >= NROWA) return;
  const float* wlA = WaL + (wv*2)*1024;
  const float* wlB = WaL + (wv*2+1)*1024;
  const float* hp = p.hT4 + lane*4;
  float aA0=0.f, aA1=0.f, aB0=0.f, aB1=0.f;
  #pragma unroll 2
  for (int k4 = 0; k4 < 256; k4 += 2) {
    float4 h0 = ld4(hp + (size_t)k4*256);
    float4 h1 = ld4(hp + (size_t)(k4+1)*256);
    float4 wa0 = ld4(wlA + k4*4);
    float4 wa1 = ld4(wlA + (k4+1)*4);
    float4 wb0 = ld4(wlB + k4*4);
    float4 wb1 = ld4(wlB + (k4+1)*4);
    aA0 = dot4f(aA0, wa0, h0); aA1 = dot4f(aA1, wa1, h1);
    aB0 = dot4f(aB0, wb0, h0); aB1 = dot4f(aB1, wb1, h1);
  }
  emitA(p, r0, aA0 + aA1, t, lane);
  if (r1 < NROWA) emitA(p, r1, aB0 + aB1, t, lane);
}

// -------- per-head addressing, thread-owns-n (n = tid) --------
__device__ void head_addr(const P& p, float* work, int head, float sim, float rown2,
                          int b, int tid, int wv, int lane) {
  float* scal = work+320; float* red = work+336; float* wg_s = work+368;
  float* wdst = work + (head ? 2416 : 1392);
  const float beta=scal[head*4+0], g=scal[head*4+1], gam=scal[head*4+2], kn=scal[head*4+3];
  const float s0=scal[8+head*3+0], s1=scal[8+head*3+1], s2=scal[8+head*3+2];
  float pp = beta * sim / (kn * sqrtf(rown2) + EPSF);
  float mx = wredmax(pp);
  if (lane == 0) red[wv] = mx;
  __syncthreads();
  mx = red[0];
  #pragma unroll
  for (int i = 1; i < 16; ++i) mx = fmaxf(mx, red[i]);
  pp = expf(pp - mx);
  float sm = wredsum(pp);
  if (lane == 0) red[16+wv] = sm;
  __syncthreads();
  sm = 0.f;
  #pragma unroll
  for (int i = 0; i < 16; ++i) sm += red[16+i];
  float* wbuf = (head ? p.ww : p.wr) + (size_t)b*NN;
  float wp = wbuf[tid];
  float wg = g * (pp / sm) + (1.f - g) * wp;
  wg_s[tid] = wg;
  __syncthreads();
  float wt = s0*wg_s[(tid+NN-1)&(NN-1)] + s1*wg + s2*wg_s[(tid+1)&(NN-1)];
  float w = powf(wt + 1e-12f, gam);
  float ps = wredsum(w);
  if (lane == 0) red[wv] = ps;
  __syncthreads();
  ps = 0.f;
  #pragma unroll
  for (int i = 0; i < 16; ++i) ps += red[i];
  w = w / (ps + EPSF);
  wbuf[tid] = w;
  wdst[tid] = w;
  __syncthreads();
}

// -------- phase A2: per-b mem chain (blocks 0..63) --------
__device__ void phaseA2(const P& p, float* work, int t, int b, int tid, int wv, int lane) {
  float* kr_s = work;        float* kw_s = work+64;
  float* e_s  = work+128;    float* a_s  = work+192;
  float* r_s  = work+256;    float* scal = work+320;   // 16
  float* wA   = work+1392;   float* wB   = work+2416;
  // gather activated gates
  if (tid < NGATE) {
    const int g = tid;
    float v = p.GY[(size_t)g*64 + b];
    if (g < 64) kr_s[g] = v;
    else if (g == 64) scal[0] = v;
    else if (g == 65) scal[1] = v;
    else if (g < 69)  scal[8 + g-66] = v;
    else if (g == 69) scal[2] = v;
    else if (g < 134) kw_s[g-70] = v;
    else if (g == 134) scal[4] = v;
    else if (g == 135) scal[5] = v;
    else if (g < 139) scal[11 + g-136] = v;
    else if (g == 139) scal[6] = v;
    else if (g < 204) e_s[g-140] = v;
    else a_s[g-204] = v;
  }
  __syncthreads();
  if (wv == 0) { float v = kr_s[lane]; float q = wredsum(v*v); if (lane==0) scal[3] = sqrtf(q); }
  else if (wv == 1) { float v = kw_s[lane]; float q = wredsum(v*v); if (lane==0) scal[7] = sqrtf(q); }
  else if (wv == 2 && lane < 2) {
    float* sv = &scal[8 + lane*3];
    float s0v=sv[0], s1v=sv[1], s2v=sv[2];
    float mxs = fmaxf(s0v, fmaxf(s1v, s2v));
    float e0=expf(s0v-mxs), e1=expf(s1v-mxs), e2=expf(s2v-mxs);
    float inv = 1.f/(e0+e1+e2);
    sv[0]=e0*inv; sv[1]=e1*inv; sv[2]=e2*inv;
  }
  __syncthreads();
  // sim pass over old mem (thread owns n = tid)
  float* mb = p.memT + (size_t)b*MM*NN;
  float simr=0.f, simw=0.f, qq=0.f;
  #pragma unroll 8
  for (int m = 0; m < MM; ++m) {
    float v = mb[(size_t)m*NN + tid];
    simr = fmaf(kr_s[m], v, simr);
    simw = fmaf(kw_s[m], v, simw);
    qq   = fmaf(v, v, qq);
  }
  head_addr(p, work, 0, simr, qq, b, tid, wv, lane);
  head_addr(p, work, 1, simw, qq, b, tid, wv, lane);
  // read (new wr, old mem) + erase/add (new ww), wave owns 4 m rows
  float4 wAr[4], wBr[4];
  #pragma unroll
  for (int c = 0; c < 4; ++c) { wAr[c] = ld4(&wA[c*256 + lane*4]); wBr[c] = ld4(&wB[c*256 + lane*4]); }
  #pragma unroll
  for (int i = 0; i < 4; ++i) {
    const int m = wv*4 + i;
    const float em = e_s[m], am = a_s[m];
    float* rowp = mb + (size_t)m*NN;
    float racc = 0.f;
    #pragma unroll
    for (int c = 0; c < 4; ++c) {
      float4 v = ld4(rowp + c*256 + lane*4);
      racc = dot4f(racc, wAr[c], v);
      float4 nv;
      nv.x = fmaf(wBr[c].x, fmaf(-em, v.x, am), v.x);
      nv.y = fmaf(wBr[c].y, fmaf(-em, v.y, am), v.y);
      nv.z = fmaf(wBr[c].z, fmaf(-em, v.z, am), v.z);
      nv.w = fmaf(wBr[c].w, fmaf(-em, v.w, am), v.w);
      st4(rowp + c*256 + lane*4, nv);
    }
    racc = wredsum(racc);
    if (lane == 0) r_s[m] = racc;
  }
  __syncthreads();
  // rinxi -> xiT4
  if (tid < II) {
    float acc = p.b_r2i[tid];
    #pragma unroll 8
    for (int m = 0; m < MM; ++m) acc = fmaf(p.W_r2iT[(size_t)m*II + tid], r_s[m], acc);
    float xv = p.x[((size_t)b*TT + t)*II + tid];
    float xi = fmaxf(xv + fmaxf(acc, 0.f), 0.f);
    p.xiT4[((size_t)(tid>>2)*64 + b)*4 + (tid&3)] = xi;
  }
}

// -------- phase B: gi-GEMV from LDS + fused GRU (all blocks) --------
__device__ void phaseB(const P& p, const float* WbL, float* work, int blk, int tid, int wv, int lane) {
  float* gi_s = work;   // 12*64
  if (wv < 6) {
    const int rr0 = wv*2, rr1 = rr0 + 1;
    const int row0 = (rr0>>2)*1024 + blk*4 + (rr0&3);
    const int row1 = (rr1>>2)*1024 + blk*4 + (rr1&3);
    const float* wlA = WbL + rr0*512;
    const float* wlB = WbL + rr1*512;
    const float* xp = p.xiT4 + lane*4;
    float aA0=p.bih[row0], aA1=0.f, aB0=p.bih[row1], aB1=0.f;
    #pragma unroll 2
    for (int k4 = 0; k4 < 128; k4 += 2) {
      float4 x0 = ld4(xp + (size_t)k4*256);
      float4 x1 = ld4(xp + (size_t)(k4+1)*256);
      float4 wa0 = ld4(wlA + k4*4);
      float4 wa1 = ld4(wlA + (k4+1)*4);
      float4 wb0 = ld4(wlB + k4*4);
      float4 wb1 = ld4(wlB + (k4+1)*4);
      aA0 = dot4f(aA0, wa0, x0); aA1 = dot4f(aA1, wa1, x1);
      aB0 = dot4f(aB0, wb0, x0); aB1 = dot4f(aB1, wb1, x1);
    }
    gi_s[rr0*64 + lane] = aA0 + aA1;
    gi_s[rr1*64 + lane] = aB0 + aB1;
  }
  __syncthreads();
  if (tid < 256) {
    const int jl = tid >> 6, b = tid & 63;
    const int j = blk*4 + jl;
    float gir = gi_s[(0*4 + jl)*64 + b];
    float giz = gi_s[(1*4 + jl)*64 + b];
    float gin = gi_s[(2*4 + jl)*64 + b];
    float ghr = p.YT[(size_t)j*64 + b];
    float ghz = p.YT[(size_t)(1024+j)*64 + b];
    float ghn = p.YT[(size_t)(2048+j)*64 + b];
    float hold = p.hT4[((size_t)(j>>2)*64 + b)*4 + (j&3)];
    float rr_ = sigmf(gir + ghr);
    float zz  = sigmf(giz + ghz);
    float nn_ = tanhf(gin + rr_*ghn);
    float hn = (1.f - zz)*nn_ + zz*hold;
    p.h[(size_t)b*HH + j] = hn;
    p.hT4[((size_t)(j>>2)*64 + b)*4 + (j&3)] = hn;
  }
}

// -------- prologue/epilogue mem transposes (blocks 0..63), 16 waves --------
__device__ void memT_build(const P& p, float* tile, int b, int wv, int lane) {
  for (int nt = 0; nt < 16; ++nt) {
    const int n0 = nt*64;
    __syncthreads();
    #pragma unroll
    for (int i = 0; i < 4; ++i) {
      const int nn = wv*4 + i;
      tile[nn*65 + lane] = p.mem0[((size_t)b*NN + n0 + nn)*MM + lane];
    }
    __syncthreads();
    #pragma unroll
    for (int i = 0; i < 4; ++i) {
      const int m = wv*4 + i;
      p.memT[((size_t)b*MM + m)*NN + n0 + lane] = tile[lane*65 + m];
    }
  }
}

__device__ void memT_out(const P& p, float* tile, int b, int wv, int lane) {
  for (int nt = 0; nt < 16; ++nt) {
    const int n0 = nt*64;
    __syncthreads();
    #pragma unroll
    for (int i = 0; i < 4; ++i) {
      const int m = wv*4 + i;
      tile[lane*65 + m] = p.memT[((size_t)b*MM + m)*NN + n0 + lane];
    }
    __syncthreads();
    #pragma unroll
    for (int i = 0; i < 4; ++i) {
      const int nn = wv*4 + i;
      p.memOut[((size_t)b*NN + n0 + nn)*MM + lane] = tile[nn*65 + lane];
    }
  }
}

// ---------------- single persistent cooperative kernel ----------------
__global__ __launch_bounds__(1024, 4) void ntm_all(P p) {
  __shared__ float smem[26688];          // 104.25 KB (gfx950 LDS = 160 KB)
  float* WaL  = smem;                    // 16*1024
  float* WbL  = smem + 16384;            // 12*512
  float* work = smem + 22528;            // 4160
  const int blk = blockIdx.x, tid = threadIdx.x;
  const int wv = tid >> 6, lane = tid & 63;
  int eb = 0;

  // ---- prologue: LDS weight residency + transposed state builds ----
  {
    const int ra = blk*16 + wv;
    if (ra < NROWA) {
      float bias; int act;
      const float* src = (ra < 3072) ? p.Whh + (size_t)ra*HH
                       : (ra < 3584) ? p.Who + (size_t)(ra-3072)*HH
                       : gate_src(p, ra-3584, bias, act);
      float* wl = WaL + wv*1024;
      #pragma unroll
      for (int c = 0; c < 4; ++c) st4(wl + c*256 + lane*4, ld4(src + c*256 + lane*4));
    }
    if (wv < 6) {
      #pragma unroll
      for (int q = 0; q < 2; ++q) {
        const int rr = wv*2 + q;
        const int row = (rr>>2)*1024 + blk*4 + (rr&3);
        float* wl = WbL + rr*512;
        const float* src = p.Wih + (size_t)row*II;
        #pragma unroll
        for (int c = 0; c < 2; ++c) st4(wl + c*256 + lane*4, ld4(src + c*256 + lane*4));
      }
    }
    if (blk < 64) {
      memT_build(p, work, blk, wv, lane);
    } else if (blk < 128) {
      const int m = blk - 64;
      if (tid < II) p.W_r2iT[(size_t)m*II + tid] = p.W_r2i[(size_t)tid*MM + m];
    } else if (blk < 192) {
      const int b = blk - 128;
      if (tid < 256) {
        float4 v = ld4(p.h + (size_t)b*HH + tid*4);
        st4(p.hT4 + ((size_t)tid*64 + b)*4, v);
      }
    }
  }
  gbar(p.flags, p.go, ++eb);

  // ---- time loop: 3 lean barriers / step ----
  for (int t = 0; t < TT; ++t) {
    phaseA(p, WaL, t, blk, wv, lane);
    gbar(p.flags, p.go, ++eb);
    if (blk < 64) phaseA2(p, work, t, blk, tid, wv, lane);
    gbar(p.flags, p.go, ++eb);
    phaseB(p, WbL, work, blk, tid, wv, lane);
    gbar(p.flags, p.go, ++eb);
  }

  // ---- epilogue: out[T-1] (Who blocks 192..223) + mem back-transpose ----
  if (blk >= 192 && blk < 224) phaseA(p, WaL, TT, blk, wv, lane);
  else if (blk < 64) memT_out(p, work, blk, wv, lane);
}

extern "C" void kernel_launch(void* const* d_in, const int* in_sizes, int n_in,
                              void* d_out, int out_size, void* d_ws, size_t ws_size,
                              hipStream_t stream) {
  const float* x    = (const float*)d_in[0];
  const float* h0   = (const float*)d_in[1];
  const float* wr0  = (const float*)d_in[2];
  const float* ww0  = (const float*)d_in[3];
  const float* mem0 = (const float*)d_in[4];
  P p;
  int i = 5;
  p.Wk_r  = (const float*)d_in[i++]; p.bk_r  = (const float*)d_in[i++];
  p.Wb_r  = (const float*)d_in[i++]; p.bb_r  = (const float*)d_in[i++];
  p.Wg_r  = (const float*)d_in[i++]; p.bg_r  = (const float*)d_in[i++];
  p.Ws_r  = (const float*)d_in[i++]; p.bs_r  = (const float*)d_in[i++];
  p.Wga_r = (const float*)d_in[i++]; p.bga_r = (const float*)d_in[i++];
  p.Wk_w  = (const float*)d_in[i++]; p.bk_w  = (const float*)d_in[i++];
  p.Wb_w  = (const float*)d_in[i++]; p.bb_w  = (const float*)d_in[i++];
  p.Wg_w  = (const float*)d_in[i++]; p.bg_w  = (const float*)d_in[i++];
  p.Ws_w  = (const float*)d_in[i++]; p.bs_w  = (const float*)d_in[i++];
  p.Wga_w = (const float*)d_in[i++]; p.bga_w = (const float*)d_in[i++];
  p.We    = (const float*)d_in[i++]; p.be    = (const float*)d_in[i++];
  p.Wa    = (const float*)d_in[i++]; p.ba    = (const float*)d_in[i++];
  p.W_r2i = (const float*)d_in[i++]; p.b_r2i = (const float*)d_in[i++];
  p.Wih   = (const float*)d_in[i++]; p.bih   = (const float*)d_in[i++];
  p.Whh   = (const float*)d_in[i++]; p.bhh   = (const float*)d_in[i++];
  p.Who   = (const float*)d_in[i++]; p.bho   = (const float*)d_in[i++];
  p.x = x; p.mem0 = mem0;

  float* out = (float*)d_out;
  p.outs   = out;                                  // (B,T,O)
  p.h      = out + (size_t)BB*TT*OO;               // (B,H) final h
  p.wr     = p.h + (size_t)BB*HH;                  // (B,N)
  p.ww     = p.wr + (size_t)BB*NN;                 // (B,N)
  p.memOut = p.ww + (size_t)BB*NN;                 // (B,N,M)

  int* bar = (int*)d_ws;                           // 4 KB barrier region
  p.flags = bar;                                   // [256]
  p.go    = bar + 256;
  float* ws = (float*)d_ws + 1024;
  p.hT4    = ws;  ws += (size_t)256*64*4;          // 256 KB
  p.YT     = ws;  ws += (size_t)3072*64;           // 768 KB
  p.GY     = ws;  ws += (size_t)NGATE*64;          // 67 KB
  p.xiT4   = ws;  ws += (size_t)128*64*4;          // 128 KB
  p.W_r2iT = ws;  ws += (size_t)MM*II;             // 128 KB
  p.memT   = ws;  ws += (size_t)BB*MM*NN;          // 16 MB   (total ~17.36 MB)

  hipMemsetAsync(d_ws, 0, 4096, stream);
  hipMemcpyAsync(p.h,  h0,  (size_t)BB*HH*sizeof(float), hipMemcpyDeviceToDevice, stream);
  hipMemcpyAsync(p.wr, wr0, (size_t)BB*NN*sizeof(float), hipMemcpyDeviceToDevice, stream);
  hipMemcpyAsync(p.ww, ww0, (size_t)BB*NN*sizeof(float), hipMemcpyDeviceToDevice, stream);

  void* args[] = { (void*)&p };
  hipLaunchCooperativeKernel((const void*)ntm_all, dim3(256), dim3(1024), args, 0, stream);
}

// Round 7
// 5342.344 us; speedup vs baseline: 1.3515x; 1.3515x over previous
//
#include <hip/hip_runtime.h>
#include <hip/hip_cooperative_groups.h>
#include <math.h>

namespace cg = cooperative_groups;

#define BB 64
#define TT 32
#define II 512
#define HH 1024
#define OO 512
#define NN 1024
#define MM 64
#define EPSF 1e-8f

#define NROWG 3584    // 3072 Whh + 512 Who rows in the big GEMV
#define ROWS_PB 20    // rows per GEMV block (blocks 64..243)

// layouts:
//  hT4  [k4 0..255][b 0..63][4]
//  xiT4 [k4 0..127][b 0..63][4]
//  YT   [row 0..3071][b]
//  memT [b][m][n]
// LDS: WaL[20][1024] (GEMV blocks) | WbL[12][512] (all) | SH[5120] (phase-multiplexed)

struct P {
  const float *Wk_r,*bk_r,*Wb_r,*bb_r,*Wg_r,*bg_r,*Ws_r,*bs_r,*Wga_r,*bga_r;
  const float *Wk_w,*bk_w,*Wb_w,*bb_w,*Wg_w,*bg_w,*Ws_w,*bs_w,*Wga_w,*bga_w;
  const float *We,*be,*Wa,*ba,*W_r2i,*b_r2i,*Wih,*bih,*Whh,*bhh,*Who,*bho;
  const float *x, *mem0;
  float *outs, *wr, *ww, *memOut, *h;
  float *hT4, *YT, *xiT4, *W_r2iT, *memT;
};

__device__ __forceinline__ float sigmf(float x){ return 1.f/(1.f+expf(-x)); }
__device__ __forceinline__ float splusf(float x){ return fmaxf(x,0.f) + log1pf(expf(-fabsf(x))); }
__device__ __forceinline__ float4 ld4(const float* p){ return *reinterpret_cast<const float4*>(p); }
__device__ __forceinline__ void st4(float* p, float4 v){ *reinterpret_cast<float4*>(p) = v; }
__device__ __forceinline__ float wredsum(float v){
  #pragma unroll
  for (int o = 32; o; o >>= 1) v += __shfl_xor(v, o);
  return v;
}
__device__ __forceinline__ float wredmax(float v){
  #pragma unroll
  for (int o = 32; o; o >>= 1) v = fmaxf(v, __shfl_xor(v, o));
  return v;
}
__device__ __forceinline__ float dot4f(float a, float4 wv, float4 vv){
  return fmaf(wv.x, vv.x, fmaf(wv.y, vv.y, fmaf(wv.z, vv.z, fmaf(wv.w, vv.w, a))));
}

// gate row descriptor (g in [0,268))
__device__ const float* gate_src(const P& p, int g, float& bias, int& act) {
  if (g < 140) {
    const int head = (g >= 70);
    const int q = g - head*70;
    if (q < 64)  { bias = (head?p.bk_w:p.bk_r)[q]; act=0; return (head?p.Wk_w:p.Wk_r)+(size_t)q*HH; }
    if (q == 64) { bias = (head?p.bb_w:p.bb_r)[0]; act=1; return head?p.Wb_w:p.Wb_r; }
    if (q == 65) { bias = (head?p.bg_w:p.bg_r)[0]; act=2; return head?p.Wg_w:p.Wg_r; }
    if (q < 69)  { bias = (head?p.bs_w:p.bs_r)[q-66]; act=5; return (head?p.Ws_w:p.Ws_r)+(size_t)(q-66)*HH; }
    bias = (head?p.bga_w:p.bga_r)[0]; act=4; return head?p.Wga_w:p.Wga_r;
  }
  if (g < 204) { const int m=g-140; bias=p.be[m]; act=2; return p.We+(size_t)m*HH; }
  const int m = g-204; bias=p.ba[m]; act=0; return p.Wa+(size_t)m*HH;
}

// -------- GEMV phase (blocks 64..243): 16 waves = 4 kgroups x 4 rowgroups(5) --------
__device__ void gemvA(const P& p, const float* WaL, float* SH, int t, int blkA,
                      int tid, int wv, int lane) {
  const int kg = wv & 3, rg = wv >> 2;
  const int kbase = kg*64;                 // k4 slice of 64 (256 k values)
  const float* hp = p.hT4 + lane*4;
  float acc[5] = {0,0,0,0,0};
  for (int kk = 0; kk < 64; kk += 4) {
    float4 hb0 = ld4(hp + (size_t)(kbase+kk+0)*256);
    float4 hb1 = ld4(hp + (size_t)(kbase+kk+1)*256);
    float4 hb2 = ld4(hp + (size_t)(kbase+kk+2)*256);
    float4 hb3 = ld4(hp + (size_t)(kbase+kk+3)*256);
    #pragma unroll
    for (int rl = 0; rl < 5; ++rl) {
      const float* wl = WaL + (size_t)(rg*5+rl)*1024;
      acc[rl] = dot4f(acc[rl], ld4(wl + (kbase+kk+0)*4), hb0);
      acc[rl] = dot4f(acc[rl], ld4(wl + (kbase+kk+1)*4), hb1);
      acc[rl] = dot4f(acc[rl], ld4(wl + (kbase+kk+2)*4), hb2);
      acc[rl] = dot4f(acc[rl], ld4(wl + (kbase+kk+3)*4), hb3);
    }
  }
  #pragma unroll
  for (int rl = 0; rl < 5; ++rl)
    SH[(kg*ROWS_PB + rg*5 + rl)*64 + lane] = acc[rl];
  __syncthreads();
  for (int idx = tid; idx < ROWS_PB*64; idx += 1024) {
    const int rloc = idx >> 6, b = idx & 63;
    float v = SH[(0*ROWS_PB+rloc)*64+b] + SH[(1*ROWS_PB+rloc)*64+b]
            + SH[(2*ROWS_PB+rloc)*64+b] + SH[(3*ROWS_PB+rloc)*64+b];
    const int r = blkA*ROWS_PB + rloc;
    if (r < 3072) {
      p.YT[(size_t)r*64 + b] = v + p.bhh[r];
    } else if (r < NROWG && t >= 1) {
      const int o = r - 3072;
      p.outs[((size_t)b*TT + (t-1))*OO + o] = sigmf(v + p.bho[o]);
    }
  }
  __syncthreads();
}

// -------- per-head addressing, thread-owns-n --------
__device__ void head_addr(const P& p, float* SH, int head, float sim, float rown2,
                          int b, int tid, int wv, int lane) {
  float* scal = SH+1344; float* red = SH+1360; float* wg_s = SH+1408;
  float* wdst = SH + (head ? 3456 : 2432);
  const float beta=scal[head*4+0], g=scal[head*4+1], gam=scal[head*4+2], kn=scal[head*4+3];
  const float s0=scal[8+head*3+0], s1=scal[8+head*3+1], s2=scal[8+head*3+2];
  float pp = beta * sim / (kn * sqrtf(rown2) + EPSF);
  float mx = wredmax(pp);
  if (lane == 0) red[wv] = mx;
  __syncthreads();
  mx = red[0];
  #pragma unroll
  for (int i = 1; i < 16; ++i) mx = fmaxf(mx, red[i]);
  pp = expf(pp - mx);
  float sm = wredsum(pp);
  if (lane == 0) red[16+wv] = sm;
  __syncthreads();
  sm = 0.f;
  #pragma unroll
  for (int i = 0; i < 16; ++i) sm += red[16+i];
  float* wbuf = (head ? p.ww : p.wr) + (size_t)b*NN;
  float wp = wbuf[tid];
  float wg = g * (pp / sm) + (1.f - g) * wp;
  wg_s[tid] = wg;
  __syncthreads();
  float wt = s0*wg_s[(tid+NN-1)&(NN-1)] + s1*wg + s2*wg_s[(tid+1)&(NN-1)];
  float w = powf(wt + 1e-12f, gam);
  float ps = wredsum(w);
  if (lane == 0) red[wv] = ps;
  __syncthreads();
  ps = 0.f;
  #pragma unroll
  for (int i = 0; i < 16; ++i) ps += red[i];
  w = w / (ps + EPSF);
  wbuf[tid] = w;
  wdst[tid] = w;
  __syncthreads();
}

// -------- A2 (blocks 0..63): gates + mem chain + rinxi, one block per b --------
__device__ void phaseA2(const P& p, float* SH, int t, int b, int tid, int wv, int lane) {
  float* h_s  = SH;          float* kr_s = SH+1024;  float* kw_s = SH+1088;
  float* e_s  = SH+1152;     float* a_s  = SH+1216;  float* r_s  = SH+1280;
  float* scal = SH+1344;     float* wA   = SH+2432;  float* wB   = SH+3456;
  h_s[tid] = p.h[(size_t)b*HH + tid];
  __syncthreads();
  // gates: wave-per-row from global weights (L2/XCD-shared)
  for (int r = wv; r < 268; r += 16) {
    float bias; int act;
    const float* wrow = gate_src(p, r, bias, act);
    float acc = 0.f;
    #pragma unroll
    for (int c = 0; c < 4; ++c)
      acc = dot4f(acc, ld4(wrow + c*256 + lane*4), ld4(&h_s[c*256 + lane*4]));
    acc = wredsum(acc);
    if (lane == 0) {
      float v = acc + bias;
      if (act==0) v = tanhf(v);
      else if (act==1) v = splusf(v);
      else if (act==2) v = sigmf(v);
      else if (act==4) v = 1.f + splusf(v);
      float* dst;
      if (r < 64) dst = &kr_s[r];
      else if (r == 64) dst = &scal[0];
      else if (r == 65) dst = &scal[1];
      else if (r < 69)  dst = &scal[8 + r-66];
      else if (r == 69) dst = &scal[2];
      else if (r < 134) dst = &kw_s[r-70];
      else if (r == 134) dst = &scal[4];
      else if (r == 135) dst = &scal[5];
      else if (r < 139) dst = &scal[11 + r-136];
      else if (r == 139) dst = &scal[6];
      else if (r < 204) dst = &e_s[r-140];
      else dst = &a_s[r-204];
      *dst = v;
    }
  }
  __syncthreads();
  if (wv == 0) { float v = kr_s[lane]; float q = wredsum(v*v); if (lane==0) scal[3] = sqrtf(q); }
  else if (wv == 1) { float v = kw_s[lane]; float q = wredsum(v*v); if (lane==0) scal[7] = sqrtf(q); }
  else if (wv == 2 && lane < 2) {
    float* sv = &scal[8 + lane*3];
    float s0v=sv[0], s1v=sv[1], s2v=sv[2];
    float mxs = fmaxf(s0v, fmaxf(s1v, s2v));
    float e0=expf(s0v-mxs), e1=expf(s1v-mxs), e2=expf(s2v-mxs);
    float inv = 1.f/(e0+e1+e2);
    sv[0]=e0*inv; sv[1]=e1*inv; sv[2]=e2*inv;
  }
  __syncthreads();
  // sim pass over old mem, thread owns n = tid, deep unroll for MLP
  float* mb = p.memT + (size_t)b*MM*NN;
  float simr=0.f, simw=0.f, qq=0.f;
  #pragma unroll 16
  for (int m = 0; m < MM; ++m) {
    float v = mb[(size_t)m*NN + tid];
    simr = fmaf(kr_s[m], v, simr);
    simw = fmaf(kw_s[m], v, simw);
    qq   = fmaf(v, v, qq);
  }
  head_addr(p, SH, 0, simr, qq, b, tid, wv, lane);
  head_addr(p, SH, 1, simw, qq, b, tid, wv, lane);
  // read + erase/add, wave owns 4 m rows
  float4 wAr[4], wBr[4];
  #pragma unroll
  for (int c = 0; c < 4; ++c) { wAr[c] = ld4(&wA[c*256 + lane*4]); wBr[c] = ld4(&wB[c*256 + lane*4]); }
  #pragma unroll
  for (int i = 0; i < 4; ++i) {
    const int m = wv*4 + i;
    const float em = e_s[m], am = a_s[m];
    float* rowp = mb + (size_t)m*NN;
    float racc = 0.f;
    #pragma unroll
    for (int c = 0; c < 4; ++c) {
      float4 v = ld4(rowp + c*256 + lane*4);
      racc = dot4f(racc, wAr[c], v);
      float4 nv;
      nv.x = fmaf(wBr[c].x, fmaf(-em, v.x, am), v.x);
      nv.y = fmaf(wBr[c].y, fmaf(-em, v.y, am), v.y);
      nv.z = fmaf(wBr[c].z, fmaf(-em, v.z, am), v.z);
      nv.w = fmaf(wBr[c].w, fmaf(-em, v.w, am), v.w);
      st4(rowp + c*256 + lane*4, nv);
    }
    racc = wredsum(racc);
    if (lane == 0) r_s[m] = racc;
  }
  __syncthreads();
  // rinxi -> xiT4
  if (tid < II) {
    float acc = p.b_r2i[tid];
    #pragma unroll 8
    for (int m = 0; m < MM; ++m) acc = fmaf(p.W_r2iT[(size_t)m*II + tid], r_s[m], acc);
    float xv = p.x[((size_t)b*TT + t)*II + tid];
    float xi = fmaxf(xv + fmaxf(acc, 0.f), 0.f);
    p.xiT4[((size_t)(tid>>2)*64 + b)*4 + (tid&3)] = xi;
  }
  __syncthreads();
}

// -------- phase B: gi GEMV K-split (4kg x 4rg x 3rows) + fused GRU, all blocks --------
__device__ void phaseB(const P& p, const float* WbL, float* SH, int blk,
                       int tid, int wv, int lane) {
  const int kg = wv & 3, rg = wv >> 2;
  const int j0 = blk * 4;
  const int kbase = kg*32;                 // k4 slice of 32 (128 k values)
  const float* xp = p.xiT4 + lane*4;
  float acc[3] = {0,0,0};
  for (int kk = 0; kk < 32; kk += 4) {
    float4 x0 = ld4(xp + (size_t)(kbase+kk+0)*256);
    float4 x1 = ld4(xp + (size_t)(kbase+kk+1)*256);
    float4 x2 = ld4(xp + (size_t)(kbase+kk+2)*256);
    float4 x3 = ld4(xp + (size_t)(kbase+kk+3)*256);
    #pragma unroll
    for (int rl = 0; rl < 3; ++rl) {
      const float* wl = WbL + (size_t)(rg*3+rl)*512;
      acc[rl] = dot4f(acc[rl], ld4(wl + (kbase+kk+0)*4), x0);
      acc[rl] = dot4f(acc[rl], ld4(wl + (kbase+kk+1)*4), x1);
      acc[rl] = dot4f(acc[rl], ld4(wl + (kbase+kk+2)*4), x2);
      acc[rl] = dot4f(acc[rl], ld4(wl + (kbase+kk+3)*4), x3);
    }
  }
  #pragma unroll
  for (int rl = 0; rl < 3; ++rl)
    SH[(kg*12 + rg*3 + rl)*64 + lane] = acc[rl];
  __syncthreads();
  float* gi = SH + 3072;
  if (tid < 768) {
    const int rr = tid >> 6, b = tid & 63;
    const int row = (rr>>2)*1024 + j0 + (rr&3);
    gi[rr*64 + b] = SH[(0*12+rr)*64+b] + SH[(1*12+rr)*64+b]
                  + SH[(2*12+rr)*64+b] + SH[(3*12+rr)*64+b] + p.bih[row];
  }
  __syncthreads();
  if (tid < 256) {
    const int jl = tid >> 6, b = tid & 63;
    const int j = j0 + jl;
    float gir = gi[(0*4 + jl)*64 + b];
    float giz = gi[(1*4 + jl)*64 + b];
    float gin = gi[(2*4 + jl)*64 + b];
    float ghr = p.YT[(size_t)j*64 + b];
    float ghz = p.YT[(size_t)(1024+j)*64 + b];
    float ghn = p.YT[(size_t)(2048+j)*64 + b];
    float hold = p.hT4[((size_t)(j>>2)*64 + b)*4 + (j&3)];
    float rr_ = sigmf(gir + ghr);
    float zz  = sigmf(giz + ghz);
    float nn_ = tanhf(gin + rr_*ghn);
    float hn = (1.f - zz)*nn_ + zz*hold;
    p.h[(size_t)b*HH + j] = hn;
    p.hT4[((size_t)(j>>2)*64 + b)*4 + (j&3)] = hn;
  }
  __syncthreads();
}

// -------- prologue/epilogue mem transposes (blocks 0..63), 16 waves --------
__device__ void memT_build(const P& p, float* tile, int b, int wv, int lane) {
  for (int nt = 0; nt < 16; ++nt) {
    const int n0 = nt*64;
    __syncthreads();
    #pragma unroll
    for (int i = 0; i < 4; ++i) {
      const int nn = wv*4 + i;
      tile[nn*65 + lane] = p.mem0[((size_t)b*NN + n0 + nn)*MM + lane];
    }
    __syncthreads();
    #pragma unroll
    for (int i = 0; i < 4; ++i) {
      const int m = wv*4 + i;
      p.memT[((size_t)b*MM + m)*NN + n0 + lane] = tile[lane*65 + m];
    }
  }
}

__device__ void memT_out(const P& p, float* tile, int b, int wv, int lane) {
  for (int nt = 0; nt < 16; ++nt) {
    const int n0 = nt*64;
    __syncthreads();
    #pragma unroll
    for (int i = 0; i < 4; ++i) {
      const int m = wv*4 + i;
      tile[lane*65 + m] = p.memT[((size_t)b*MM + m)*NN + n0 + lane];
    }
    __syncthreads();
    #pragma unroll
    for (int i = 0; i < 4; ++i) {
      const int nn = wv*4 + i;
      p.memOut[((size_t)b*NN + n0 + nn)*MM + lane] = tile[nn*65 + lane];
    }
  }
}

// ---------------- single persistent cooperative kernel ----------------
__global__ __launch_bounds__(1024, 4) void ntm_all(P p) {
  __shared__ float smem[31744];          // 124 KB: WaL 80K | WbL 24K | SH 20K
  float* WaL = smem;                     // 20*1024
  float* WbL = smem + 20480;             // 12*512
  float* SH  = smem + 26624;             // 5120
  cg::grid_group grid = cg::this_grid();
  const int blk = blockIdx.x, tid = threadIdx.x;
  const int wv = tid >> 6, lane = tid & 63;

  // ---- prologue ----
  if (wv < 6) {                          // WbL: 12 Wih rows (all blocks)
    #pragma unroll
    for (int q = 0; q < 2; ++q) {
      const int rr = wv*2 + q;
      const int row = (rr>>2)*1024 + blk*4 + (rr&3);
      float* wl = WbL + rr*512;
      const float* src = p.Wih + (size_t)row*II;
      #pragma unroll
      for (int c = 0; c < 2; ++c) st4(wl + c*256 + lane*4, ld4(src + c*256 + lane*4));
    }
  }
  if (blk >= 64 && blk < 244) {          // WaL: 20 [Whh;Who] rows
    for (int rloc = wv; rloc < ROWS_PB; rloc += 16) {
      const int r = (blk-64)*ROWS_PB + rloc;
      if (r < NROWG) {
        const float* src = (r < 3072) ? p.Whh + (size_t)r*HH : p.Who + (size_t)(r-3072)*HH;
        float* wl = WaL + (size_t)rloc*1024;
        #pragma unroll
        for (int c = 0; c < 4; ++c) st4(wl + c*256 + lane*4, ld4(src + c*256 + lane*4));
      }
    }
  } else if (blk < 64) {
    memT_build(p, SH, blk, wv, lane);
    __syncthreads();
    if (tid < 256) {                     // hT4 init for b = blk
      float4 v = ld4(p.h + (size_t)blk*HH + tid*4);
      st4(p.hT4 + ((size_t)tid*64 + blk)*4, v);
    }
  } else {                               // blocks 244..255: W_r2iT
    #pragma unroll
    for (int i = 0; i < 6; ++i) {
      const int m = (blk-244)*6 + i;
      if (m < MM)
        for (int ii = tid; ii < II; ii += 1024)
          p.W_r2iT[(size_t)m*II + ii] = p.W_r2i[(size_t)ii*MM + m];
    }
  }
  grid.sync();

  // ---- time loop: 2 grid syncs / step ----
  for (int t = 0; t < TT; ++t) {
    if (blk < 64) phaseA2(p, SH, t, blk, tid, wv, lane);
    else if (blk < 244) gemvA(p, WaL, SH, t, blk-64, tid, wv, lane);
    grid.sync();
    phaseB(p, WbL, SH, blk, tid, wv, lane);
    grid.sync();
  }

  // ---- epilogue: outs[T-1] + mem back-transpose ----
  if (blk >= 64 && blk < 244) gemvA(p, WaL, SH, TT, blk-64, tid, wv, lane);
  else if (blk < 64) memT_out(p, SH, blk, wv, lane);
}

extern "C" void kernel_launch(void* const* d_in, const int* in_sizes, int n_in,
                              void* d_out, int out_size, void* d_ws, size_t ws_size,
                              hipStream_t stream) {
  const float* x    = (const float*)d_in[0];
  const float* h0   = (const float*)d_in[1];
  const float* wr0  = (const float*)d_in[2];
  const float* ww0  = (const float*)d_in[3];
  const float* mem0 = (const float*)d_in[4];
  P p;
  int i = 5;
  p.Wk_r  = (const float*)d_in[i++]; p.bk_r  = (const float*)d_in[i++];
  p.Wb_r  = (const float*)d_in[i++]; p.bb_r  = (const float*)d_in[i++];
  p.Wg_r  = (const float*)d_in[i++]; p.bg_r  = (const float*)d_in[i++];
  p.Ws_r  = (const float*)d_in[i++]; p.bs_r  = (const float*)d_in[i++];
  p.Wga_r = (const float*)d_in[i++]; p.bga_r = (const float*)d_in[i++];
  p.Wk_w  = (const float*)d_in[i++]; p.bk_w  = (const float*)d_in[i++];
  p.Wb_w  = (const float*)d_in[i++]; p.bb_w  = (const float*)d_in[i++];
  p.Wg_w  = (const float*)d_in[i++]; p.bg_w  = (const float*)d_in[i++];
  p.Ws_w  = (const float*)d_in[i++]; p.bs_w  = (const float*)d_in[i++];
  p.Wga_w = (const float*)d_in[i++]; p.bga_w = (const float*)d_in[i++];
  p.We    = (const float*)d_in[i++]; p.be    = (const float*)d_in[i++];
  p.Wa    = (const float*)d_in[i++]; p.ba    = (const float*)d_in[i++];
  p.W_r2i = (const float*)d_in[i++]; p.b_r2i = (const float*)d_in[i++];
  p.Wih   = (const float*)d_in[i++]; p.bih   = (const float*)d_in[i++];
  p.Whh   = (const float*)d_in[i++]; p.bhh   = (const float*)d_in[i++];
  p.Who   = (const float*)d_in[i++]; p.bho   = (const float*)d_in[i++];
  p.x = x; p.mem0 = mem0;

  float* out = (float*)d_out;
  p.outs   = out;                                  // (B,T,O)
  p.h      = out + (size_t)BB*TT*OO;               // (B,H) final h
  p.wr     = p.h + (size_t)BB*HH;                  // (B,N)
  p.ww     = p.wr + (size_t)BB*NN;                 // (B,N)
  p.memOut = p.ww + (size_t)BB*NN;                 // (B,N,M)

  float* ws = (float*)d_ws;
  p.hT4    = ws;  ws += (size_t)256*64*4;          // 256 KB
  p.YT     = ws;  ws += (size_t)3072*64;           // 768 KB
  p.xiT4   = ws;  ws += (size_t)128*64*4;          // 128 KB
  p.W_r2iT = ws;  ws += (size_t)MM*II;             // 128 KB
  p.memT   = ws;  ws += (size_t)BB*MM*NN;          // 16 MB   (total ~17.3 MB)

  hipMemcpyAsync(p.h,  h0,  (size_t)BB*HH*sizeof(float), hipMemcpyDeviceToDevice, stream);
  hipMemcpyAsync(p.wr, wr0, (size_t)BB*NN*sizeof(float), hipMemcpyDeviceToDevice, stream);
  hipMemcpyAsync(p.ww, ww0, (size_t)BB*NN*sizeof(float), hipMemcpyDeviceToDevice, stream);

  void* args[] = { (void*)&p };
  hipLaunchCooperativeKernel((const void*)ntm_all, dim3(256), dim3(1024), args, 0, stream);
}

// Round 8
// 5165.601 us; speedup vs baseline: 1.3978x; 1.0342x over previous
//
#include <hip/hip_runtime.h>
#include <hip/hip_cooperative_groups.h>
#include <math.h>

namespace cg = cooperative_groups;

#define BB 64
#define TT 32
#define II 512
#define HH 1024
#define OO 512
#define NN 1024
#define MM 64
#define EPSF 1e-8f

// virtual GEMV row space (K=1024, all dot h):
//   [0,268)     gate rows  -> GY (activated)
//   [268,3340)  Whh rows   -> YT (+bhh)
//   [3340,3852) Who rows   -> outs[t-1] (sigmoid)
#define NROWV 3852
#define ROWS_PB 21      // valid rows per GEMV block (192 blocks: 64..255)
#define ROWS_PAD 24     // padded to 4 rowgroups x 6
#define NGPROD 13       // blocks 64..76 own all gate rows (13*21=273>=268)

struct P {
  const float *Wk_r,*bk_r,*Wb_r,*bb_r,*Wg_r,*bg_r,*Ws_r,*bs_r,*Wga_r,*bga_r;
  const float *Wk_w,*bk_w,*Wb_w,*bb_w,*Wg_w,*bg_w,*Ws_w,*bs_w,*Wga_w,*bga_w;
  const float *We,*be,*Wa,*ba,*W_r2i,*b_r2i,*Wih,*bih,*Whh,*bhh,*Who,*bho;
  const float *x, *mem0;
  float *outs, *wr, *ww, *memOut, *h;
  float *hT4, *YT, *GY, *xiT4, *W_r2iT, *memT;
  int *gateCnt;
};

__device__ __forceinline__ float sigmf(float x){ return 1.f/(1.f+expf(-x)); }
__device__ __forceinline__ float splusf(float x){ return fmaxf(x,0.f) + log1pf(expf(-fabsf(x))); }
__device__ __forceinline__ float4 ld4(const float* p){ return *reinterpret_cast<const float4*>(p); }
__device__ __forceinline__ void st4(float* p, float4 v){ *reinterpret_cast<float4*>(p) = v; }
__device__ __forceinline__ float wredsum(float v){
  #pragma unroll
  for (int o = 32; o; o >>= 1) v += __shfl_xor(v, o);
  return v;
}
__device__ __forceinline__ float wredmax(float v){
  #pragma unroll
  for (int o = 32; o; o >>= 1) v = fmaxf(v, __shfl_xor(v, o));
  return v;
}
__device__ __forceinline__ float dot4f(float a, float4 wv, float4 vv){
  return fmaf(wv.x, vv.x, fmaf(wv.y, vv.y, fmaf(wv.z, vv.z, fmaf(wv.w, vv.w, a))));
}

// gate row descriptor (g in [0,268))
__device__ const float* gate_src(const P& p, int g, float& bias, int& act) {
  if (g < 140) {
    const int head = (g >= 70);
    const int q = g - head*70;
    if (q < 64)  { bias = (head?p.bk_w:p.bk_r)[q]; act=0; return (head?p.Wk_w:p.Wk_r)+(size_t)q*HH; }
    if (q == 64) { bias = (head?p.bb_w:p.bb_r)[0]; act=1; return head?p.Wb_w:p.Wb_r; }
    if (q == 65) { bias = (head?p.bg_w:p.bg_r)[0]; act=2; return head?p.Wg_w:p.Wg_r; }
    if (q < 69)  { bias = (head?p.bs_w:p.bs_r)[q-66]; act=5; return (head?p.Ws_w:p.Ws_r)+(size_t)(q-66)*HH; }
    bias = (head?p.bga_w:p.bga_r)[0]; act=4; return head?p.Wga_w:p.Wga_r;
  }
  if (g < 204) { const int m=g-140; bias=p.be[m]; act=2; return p.We+(size_t)m*HH; }
  const int m = g-204; bias=p.ba[m]; act=0; return p.Wa+(size_t)m*HH;
}

// -------- GEMV phase (blocks 64..255): K-split 4kg x 4rg x 6rows, LDS weights --------
__device__ void gemvA(const P& p, const float* WaL, float* SH, int t, int row0,
                      bool gateprod, int tid, int wv, int lane) {
  const int kg = wv & 3, rg = wv >> 2;
  const int kbase = kg*64;
  const float* hp = p.hT4 + lane*4;
  float acc[6] = {0,0,0,0,0,0};
  for (int kk = 0; kk < 64; kk += 4) {
    float4 hb0 = ld4(hp + (size_t)(kbase+kk+0)*256);
    float4 hb1 = ld4(hp + (size_t)(kbase+kk+1)*256);
    float4 hb2 = ld4(hp + (size_t)(kbase+kk+2)*256);
    float4 hb3 = ld4(hp + (size_t)(kbase+kk+3)*256);
    #pragma unroll
    for (int rl = 0; rl < 6; ++rl) {
      const float* wl = WaL + (size_t)(rg*6+rl)*1024;
      acc[rl] = dot4f(acc[rl], ld4(wl + (kbase+kk+0)*4), hb0);
      acc[rl] = dot4f(acc[rl], ld4(wl + (kbase+kk+1)*4), hb1);
      acc[rl] = dot4f(acc[rl], ld4(wl + (kbase+kk+2)*4), hb2);
      acc[rl] = dot4f(acc[rl], ld4(wl + (kbase+kk+3)*4), hb3);
    }
  }
  #pragma unroll
  for (int rl = 0; rl < 6; ++rl)
    SH[(kg*ROWS_PAD + rg*6 + rl)*64 + lane] = acc[rl];
  __syncthreads();
  for (int idx = tid; idx < ROWS_PAD*64; idx += 1024) {
    const int rloc = idx >> 6, b = idx & 63;
    if (rloc >= ROWS_PB) continue;
    const int r = row0 + rloc;
    if (r >= NROWV) continue;
    float v = SH[(0*ROWS_PAD+rloc)*64+b] + SH[(1*ROWS_PAD+rloc)*64+b]
            + SH[(2*ROWS_PAD+rloc)*64+b] + SH[(3*ROWS_PAD+rloc)*64+b];
    if (r < 268) {
      float bias; int act;
      gate_src(p, r, bias, act);
      v += bias;
      if (act==0) v = tanhf(v);
      else if (act==1) v = splusf(v);
      else if (act==2) v = sigmf(v);
      else if (act==4) v = 1.f + splusf(v);
      p.GY[(size_t)r*64 + b] = v;
    } else if (r < 3340) {
      const int rr = r - 268;
      p.YT[(size_t)rr*64 + b] = v + p.bhh[rr];
    } else if (t >= 1) {
      const int o = r - 3340;
      p.outs[((size_t)b*TT + (t-1))*OO + o] = sigmf(v + p.bho[o]);
    }
  }
  __syncthreads();
  if (gateprod && tid == 0) {
    __builtin_amdgcn_fence(__ATOMIC_RELEASE, "agent");
    __hip_atomic_fetch_add(p.gateCnt, 1, __ATOMIC_RELAXED, __HIP_MEMORY_SCOPE_AGENT);
  }
}

// -------- per-head addressing, thread-owns-n (n = tid) --------
__device__ void head_addr(const P& p, float* SH, int head, float sim, float rown2,
                          int b, int tid, int wv, int lane) {
  float* scal = SH+320; float* red = SH+336; float* wg_s = SH+384;
  float* wdst = SH + (head ? 2432 : 1408);
  const float beta=scal[head*4+0], g=scal[head*4+1], gam=scal[head*4+2], kn=scal[head*4+3];
  const float s0=scal[8+head*3+0], s1=scal[8+head*3+1], s2=scal[8+head*3+2];
  float pp = beta * sim / (kn * sqrtf(rown2) + EPSF);
  float mx = wredmax(pp);
  if (lane == 0) red[wv] = mx;
  __syncthreads();
  mx = red[0];
  #pragma unroll
  for (int i = 1; i < 16; ++i) mx = fmaxf(mx, red[i]);
  pp = expf(pp - mx);
  float sm = wredsum(pp);
  if (lane == 0) red[16+wv] = sm;
  __syncthreads();
  sm = 0.f;
  #pragma unroll
  for (int i = 0; i < 16; ++i) sm += red[16+i];
  float* wbuf = (head ? p.ww : p.wr) + (size_t)b*NN;
  float wp = wbuf[tid];
  float wg = g * (pp / sm) + (1.f - g) * wp;
  wg_s[tid] = wg;
  __syncthreads();
  float wt = s0*wg_s[(tid+NN-1)&(NN-1)] + s1*wg + s2*wg_s[(tid+1)&(NN-1)];
  float w = powf(wt + 1e-12f, gam);
  float ps = wredsum(w);
  if (lane == 0) red[wv] = ps;
  __syncthreads();
  ps = 0.f;
  #pragma unroll
  for (int i = 0; i < 16; ++i) ps += red[i];
  w = w / (ps + EPSF);
  wbuf[tid] = w;
  wdst[tid] = w;
  __syncthreads();
}

// -------- A2 (blocks 0..63): wait gates -> mem chain -> rinxi --------
__device__ void phaseA2(const P& p, float* SH, int t, int b, int tid, int wv, int lane) {
  float* kr_s = SH;        float* kw_s = SH+64;
  float* e_s  = SH+128;    float* a_s  = SH+192;
  float* r_s  = SH+256;    float* scal = SH+320;
  float* wA   = SH+1408;   float* wB   = SH+2432;
  // wait for gate rows (13 producer blocks this step)
  if (tid == 0) {
    const int target = NGPROD*(t+1);
    while (__hip_atomic_load(p.gateCnt, __ATOMIC_RELAXED, __HIP_MEMORY_SCOPE_AGENT) < target)
      __builtin_amdgcn_s_sleep(4);
  }
  __syncthreads();
  __builtin_amdgcn_fence(__ATOMIC_ACQUIRE, "agent");
  // gather activated gates
  if (tid < 268) {
    const int g = tid;
    float v = p.GY[(size_t)g*64 + b];
    if (g < 64) kr_s[g] = v;
    else if (g == 64) scal[0] = v;
    else if (g == 65) scal[1] = v;
    else if (g < 69)  scal[8 + g-66] = v;
    else if (g == 69) scal[2] = v;
    else if (g < 134) kw_s[g-70] = v;
    else if (g == 134) scal[4] = v;
    else if (g == 135) scal[5] = v;
    else if (g < 139) scal[11 + g-136] = v;
    else if (g == 139) scal[6] = v;
    else if (g < 204) e_s[g-140] = v;
    else a_s[g-204] = v;
  }
  __syncthreads();
  if (wv == 0) { float v = kr_s[lane]; float q = wredsum(v*v); if (lane==0) scal[3] = sqrtf(q); }
  else if (wv == 1) { float v = kw_s[lane]; float q = wredsum(v*v); if (lane==0) scal[7] = sqrtf(q); }
  else if (wv == 2 && lane < 2) {
    float* sv = &scal[8 + lane*3];
    float s0v=sv[0], s1v=sv[1], s2v=sv[2];
    float mxs = fmaxf(s0v, fmaxf(s1v, s2v));
    float e0=expf(s0v-mxs), e1=expf(s1v-mxs), e2=expf(s2v-mxs);
    float inv = 1.f/(e0+e1+e2);
    sv[0]=e0*inv; sv[1]=e1*inv; sv[2]=e2*inv;
  }
  __syncthreads();
  // combined sim pass over old mem, thread owns n = tid
  float* mb = p.memT + (size_t)b*MM*NN;
  float simr=0.f, simw=0.f, qq=0.f;
  #pragma unroll 16
  for (int m = 0; m < MM; ++m) {
    float v = mb[(size_t)m*NN + tid];
    simr = fmaf(kr_s[m], v, simr);
    simw = fmaf(kw_s[m], v, simw);
    qq   = fmaf(v, v, qq);
  }
  head_addr(p, SH, 0, simr, qq, b, tid, wv, lane);
  head_addr(p, SH, 1, simw, qq, b, tid, wv, lane);
  // read + erase/add, wave owns 4 m rows
  float4 wAr[4], wBr[4];
  #pragma unroll
  for (int c = 0; c < 4; ++c) { wAr[c] = ld4(&wA[c*256 + lane*4]); wBr[c] = ld4(&wB[c*256 + lane*4]); }
  #pragma unroll
  for (int i = 0; i < 4; ++i) {
    const int m = wv*4 + i;
    const float em = e_s[m], am = a_s[m];
    float* rowp = mb + (size_t)m*NN;
    float racc = 0.f;
    #pragma unroll
    for (int c = 0; c < 4; ++c) {
      float4 v = ld4(rowp + c*256 + lane*4);
      racc = dot4f(racc, wAr[c], v);
      float4 nv;
      nv.x = fmaf(wBr[c].x, fmaf(-em, v.x, am), v.x);
      nv.y = fmaf(wBr[c].y, fmaf(-em, v.y, am), v.y);
      nv.z = fmaf(wBr[c].z, fmaf(-em, v.z, am), v.z);
      nv.w = fmaf(wBr[c].w, fmaf(-em, v.w, am), v.w);
      st4(rowp + c*256 + lane*4, nv);
    }
    racc = wredsum(racc);
    if (lane == 0) r_s[m] = racc;
  }
  __syncthreads();
  // rinxi -> xiT4
  if (tid < II) {
    float acc = p.b_r2i[tid];
    #pragma unroll 8
    for (int m = 0; m < MM; ++m) acc = fmaf(p.W_r2iT[(size_t)m*II + tid], r_s[m], acc);
    float xv = p.x[((size_t)b*TT + t)*II + tid];
    float xi = fmaxf(xv + fmaxf(acc, 0.f), 0.f);
    p.xiT4[((size_t)(tid>>2)*64 + b)*4 + (tid&3)] = xi;
  }
  __syncthreads();
}

// -------- phase B: gi GEMV K-split + fused GRU, all 256 blocks --------
__device__ void phaseB(const P& p, const float* WbL, float* SH, int blk,
                       int tid, int wv, int lane) {
  const int kg = wv & 3, rg = wv >> 2;
  const int j0 = blk * 4;
  const int kbase = kg*32;
  const float* xp = p.xiT4 + lane*4;
  float acc[3] = {0,0,0};
  for (int kk = 0; kk < 32; kk += 4) {
    float4 x0 = ld4(xp + (size_t)(kbase+kk+0)*256);
    float4 x1 = ld4(xp + (size_t)(kbase+kk+1)*256);
    float4 x2 = ld4(xp + (size_t)(kbase+kk+2)*256);
    float4 x3 = ld4(xp + (size_t)(kbase+kk+3)*256);
    #pragma unroll
    for (int rl = 0; rl < 3; ++rl) {
      const float* wl = WbL + (size_t)(rg*3+rl)*512;
      acc[rl] = dot4f(acc[rl], ld4(wl + (kbase+kk+0)*4), x0);
      acc[rl] = dot4f(acc[rl], ld4(wl + (kbase+kk+1)*4), x1);
      acc[rl] = dot4f(acc[rl], ld4(wl + (kbase+kk+2)*4), x2);
      acc[rl] = dot4f(acc[rl], ld4(wl + (kbase+kk+3)*4), x3);
    }
  }
  #pragma unroll
  for (int rl = 0; rl < 3; ++rl)
    SH[(kg*12 + rg*3 + rl)*64 + lane] = acc[rl];
  __syncthreads();
  float* gi = SH + 3072;
  if (tid < 768) {
    const int rr = tid >> 6, b = tid & 63;
    const int row = (rr>>2)*1024 + j0 + (rr&3);
    gi[rr*64 + b] = SH[(0*12+rr)*64+b] + SH[(1*12+rr)*64+b]
                  + SH[(2*12+rr)*64+b] + SH[(3*12+rr)*64+b] + p.bih[row];
  }
  __syncthreads();
  if (tid < 256) {
    const int jl = tid >> 6, b = tid & 63;
    const int j = j0 + jl;
    float gir = gi[(0*4 + jl)*64 + b];
    float giz = gi[(1*4 + jl)*64 + b];
    float gin = gi[(2*4 + jl)*64 + b];
    float ghr = p.YT[(size_t)j*64 + b];
    float ghz = p.YT[(size_t)(1024+j)*64 + b];
    float ghn = p.YT[(size_t)(2048+j)*64 + b];
    float hold = p.hT4[((size_t)(j>>2)*64 + b)*4 + (j&3)];
    float rr_ = sigmf(gir + ghr);
    float zz  = sigmf(giz + ghz);
    float nn_ = tanhf(gin + rr_*ghn);
    float hn = (1.f - zz)*nn_ + zz*hold;
    p.h[(size_t)b*HH + j] = hn;
    p.hT4[((size_t)(j>>2)*64 + b)*4 + (j&3)] = hn;
  }
  __syncthreads();
}

// -------- prologue/epilogue mem transposes (blocks 0..63), 16 waves --------
__device__ void memT_build(const P& p, float* tile, int b, int wv, int lane) {
  for (int nt = 0; nt < 16; ++nt) {
    const int n0 = nt*64;
    __syncthreads();
    #pragma unroll
    for (int i = 0; i < 4; ++i) {
      const int nn = wv*4 + i;
      tile[nn*65 + lane] = p.mem0[((size_t)b*NN + n0 + nn)*MM + lane];
    }
    __syncthreads();
    #pragma unroll
    for (int i = 0; i < 4; ++i) {
      const int m = wv*4 + i;
      p.memT[((size_t)b*MM + m)*NN + n0 + lane] = tile[lane*65 + m];
    }
  }
}

__device__ void memT_out(const P& p, float* tile, int b, int wv, int lane) {
  for (int nt = 0; nt < 16; ++nt) {
    const int n0 = nt*64;
    __syncthreads();
    #pragma unroll
    for (int i = 0; i < 4; ++i) {
      const int m = wv*4 + i;
      tile[lane*65 + m] = p.memT[((size_t)b*MM + m)*NN + n0 + lane];
    }
    __syncthreads();
    #pragma unroll
    for (int i = 0; i < 4; ++i) {
      const int nn = wv*4 + i;
      p.memOut[((size_t)b*NN + n0 + nn)*MM + lane] = tile[nn*65 + lane];
    }
  }
}

// ---------------- single persistent cooperative kernel ----------------
__global__ __launch_bounds__(1024, 4) void ntm_all(P p) {
  __shared__ float smem[36864];          // 144 KB: WaL 96K | WbL 24K | SH 24K
  float* WaL = smem;                     // 24*1024
  float* WbL = smem + 24576;             // 12*512
  float* SH  = smem + 30720;             // 6144
  cg::grid_group grid = cg::this_grid();
  const int blk = blockIdx.x, tid = threadIdx.x;
  const int wv = tid >> 6, lane = tid & 63;
  const int row0 = (blk - 64) * ROWS_PB;
  const bool gateprod = (blk >= 64 && blk < 64 + NGPROD);

  // ---- prologue ----
  if (wv < 6) {                          // WbL: 12 Wih rows (all blocks)
    #pragma unroll
    for (int q = 0; q < 2; ++q) {
      const int rr = wv*2 + q;
      const int row = (rr>>2)*1024 + blk*4 + (rr&3);
      float* wl = WbL + rr*512;
      const float* src = p.Wih + (size_t)row*II;
      #pragma unroll
      for (int c = 0; c < 2; ++c) st4(wl + c*256 + lane*4, ld4(src + c*256 + lane*4));
    }
  }
  if (blk >= 64) {                       // WaL: 24 rows (21 valid + pad)
    for (int rloc = wv; rloc < ROWS_PAD; rloc += 16) {
      const int r = row0 + rloc;
      float* wl = WaL + (size_t)rloc*1024;
      const bool valid = (rloc < ROWS_PB) && (r < NROWV);
      if (valid) {
        float bias; int act;
        const float* src = (r < 268) ? gate_src(p, r, bias, act)
                         : (r < 3340) ? p.Whh + (size_t)(r-268)*HH
                         : p.Who + (size_t)(r-3340)*HH;
        #pragma unroll
        for (int c = 0; c < 4; ++c) st4(wl + c*256 + lane*4, ld4(src + c*256 + lane*4));
      } else {
        const float4 z = make_float4(0.f,0.f,0.f,0.f);
        #pragma unroll
        for (int c = 0; c < 4; ++c) st4(wl + c*256 + lane*4, z);
      }
    }
  } else {                               // blocks 0..63: state builds
    memT_build(p, SH, blk, wv, lane);
    __syncthreads();
    if (tid < 256) {
      float4 v = ld4(p.h + (size_t)blk*HH + tid*4);
      st4(p.hT4 + ((size_t)tid*64 + blk)*4, v);
    }
    if (tid < II) p.W_r2iT[(size_t)blk*II + tid] = p.W_r2i[(size_t)tid*MM + blk];
  }
  grid.sync();

  // ---- time loop: 2 grid syncs / step (+ intra-phase gate flag) ----
  for (int t = 0; t < TT; ++t) {
    if (blk < 64) phaseA2(p, SH, t, blk, tid, wv, lane);
    else gemvA(p, WaL, SH, t, row0, gateprod, tid, wv, lane);
    grid.sync();
    phaseB(p, WbL, SH, blk, tid, wv, lane);
    grid.sync();
  }

  // ---- epilogue: outs[T-1] + mem back-transpose ----
  if (blk >= 64) gemvA(p, WaL, SH, TT, row0, false, tid, wv, lane);
  else memT_out(p, SH, blk, wv, lane);
}

extern "C" void kernel_launch(void* const* d_in, const int* in_sizes, int n_in,
                              void* d_out, int out_size, void* d_ws, size_t ws_size,
                              hipStream_t stream) {
  const float* x    = (const float*)d_in[0];
  const float* h0   = (const float*)d_in[1];
  const float* wr0  = (const float*)d_in[2];
  const float* ww0  = (const float*)d_in[3];
  const float* mem0 = (const float*)d_in[4];
  P p;
  int i = 5;
  p.Wk_r  = (const float*)d_in[i++]; p.bk_r  = (const float*)d_in[i++];
  p.Wb_r  = (const float*)d_in[i++]; p.bb_r  = (const float*)d_in[i++];
  p.Wg_r  = (const float*)d_in[i++]; p.bg_r  = (const float*)d_in[i++];
  p.Ws_r  = (const float*)d_in[i++]; p.bs_r  = (const float*)d_in[i++];
  p.Wga_r = (const float*)d_in[i++]; p.bga_r = (const float*)d_in[i++];
  p.Wk_w  = (const float*)d_in[i++]; p.bk_w  = (const float*)d_in[i++];
  p.Wb_w  = (const float*)d_in[i++]; p.bb_w  = (const float*)d_in[i++];
  p.Wg_w  = (const float*)d_in[i++]; p.bg_w  = (const float*)d_in[i++];
  p.Ws_w  = (const float*)d_in[i++]; p.bs_w  = (const float*)d_in[i++];
  p.Wga_w = (const float*)d_in[i++]; p.bga_w = (const float*)d_in[i++];
  p.We    = (const float*)d_in[i++]; p.be    = (const float*)d_in[i++];
  p.Wa    = (const float*)d_in[i++]; p.ba    = (const float*)d_in[i++];
  p.W_r2i = (const float*)d_in[i++]; p.b_r2i = (const float*)d_in[i++];
  p.Wih   = (const float*)d_in[i++]; p.bih   = (const float*)d_in[i++];
  p.Whh   = (const float*)d_in[i++]; p.bhh   = (const float*)d_in[i++];
  p.Who   = (const float*)d_in[i++]; p.bho   = (const float*)d_in[i++];
  p.x = x; p.mem0 = mem0;

  float* out = (float*)d_out;
  p.outs   = out;                                  // (B,T,O)
  p.h      = out + (size_t)BB*TT*OO;               // (B,H) final h
  p.wr     = p.h + (size_t)BB*HH;                  // (B,N)
  p.ww     = p.wr + (size_t)BB*NN;                 // (B,N)
  p.memOut = p.ww + (size_t)BB*NN;                 // (B,N,M)

  p.gateCnt = (int*)d_ws;                          // 4 KB flag region
  float* ws = (float*)d_ws + 1024;
  p.hT4    = ws;  ws += (size_t)256*64*4;          // 256 KB
  p.YT     = ws;  ws += (size_t)3072*64;           // 768 KB
  p.GY     = ws;  ws += (size_t)268*64;            // 67 KB
  p.xiT4   = ws;  ws += (size_t)128*64*4;          // 128 KB
  p.W_r2iT = ws;  ws += (size_t)MM*II;             // 128 KB
  p.memT   = ws;  ws += (size_t)BB*MM*NN;          // 16 MB   (total ~17.4 MB)

  hipMemsetAsync(d_ws, 0, 4096, stream);
  hipMemcpyAsync(p.h,  h0,  (size_t)BB*HH*sizeof(float), hipMemcpyDeviceToDevice, stream);
  hipMemcpyAsync(p.wr, wr0, (size_t)BB*NN*sizeof(float), hipMemcpyDeviceToDevice, stream);
  hipMemcpyAsync(p.ww, ww0, (size_t)BB*NN*sizeof(float), hipMemcpyDeviceToDevice, stream);

  void* args[] = { (void*)&p };
  hipLaunchCooperativeKernel((const void*)ntm_all, dim3(256), dim3(1024), args, 0, stream);
}